// Round 1
// baseline (17110.042 us; speedup 1.0000x reference)
//
#include <hip/hip_runtime.h>
#include <hip/hip_bf16.h>

#define NB 16
#define SB 2048
#define DB 256
#define EB 512
#define LB 4
#define NSEG_CAP 1024
#define GRID_MAIN 256

typedef __bf16 bf16x8 __attribute__((ext_vector_type(8)));
typedef float  f32x4  __attribute__((ext_vector_type(4)));

// ---------------- workspace layout (bytes) ----------------
#define OFF_XBF   0ull
#define SZ_XBF    (16ull*2048*256*2)          // x as bf16
#define OFF_W0    (OFF_XBF + SZ_XBF)          // layer0 concat W (2048 x 768) bf16
#define SZ_W0     (2048ull*768*2)
#define OFF_W1    (OFF_W0 + SZ_W0)            // layers 1..3 concat W (2048 x 1024) bf16
#define SZ_WX     (2048ull*1024*2)
#define OFF_W2    (OFF_W1 + SZ_WX)
#define OFF_W3    (OFF_W2 + SZ_WX)
#define OFF_BIAS  (OFF_W3 + SZ_WX)            // 4*2048 f32 (b_ih+b_hh)
#define OFF_H     (OFF_BIAS + 4ull*2048*4)    // [l][parity][seg][e] bf16
#define SZ_H      (4ull*2*NSEG_CAP*EB*2)
#define OFF_C     (OFF_H + SZ_H)              // [l][seg][e] f32
#define SZ_C      (4ull*NSEG_CAP*EB*4)
#define OFF_SROW  (OFF_C + SZ_C)
#define OFF_SSTART (OFF_SROW  + 4ull*NSEG_CAP)
#define OFF_SLEN   (OFF_SSTART + 4ull*NSEG_CAP)
#define OFF_SSLOT  (OFF_SLEN  + 4ull*NSEG_CAP)
#define OFF_ACT   (OFF_SSLOT + 4ull*NSEG_CAP) // active[r], 2048 ints
#define OFF_META  (OFF_ACT + 4ull*2048)       // [0]=NSEG [1]=maxlen
#define OFF_BAR   (OFF_META + 256ull)         // cnt[2560] + gen
#define BAR_WORDS 2564

__device__ __forceinline__ unsigned short f2bf(float f) {
  union { float f; unsigned u; } v; v.f = f;
  unsigned r = v.u + 0x7FFFu + ((v.u >> 16) & 1u);
  return (unsigned short)(r >> 16);
}
__device__ __forceinline__ float sigf(float x) {
  x = fminf(30.f, fmaxf(-30.f, x));
  return 1.f / (1.f + __expf(-x));
}
__device__ __forceinline__ float tanhx(float x) {
  x = fminf(15.f, fmaxf(-15.f, x));
  float e = __expf(-2.f * x);
  return (1.f - e) / (1.f + e);
}

// ---------------- kernel 1: conversions + zeroing ----------------
__global__ void k_conv(const float* __restrict__ x, const float* __restrict__ wih0,
                       const float* __restrict__ wihr, const float* __restrict__ whh,
                       const float* __restrict__ bih, const float* __restrict__ bhh,
                       float* __restrict__ dout, int out_size, char* __restrict__ ws) {
  long long gid = (long long)blockIdx.x * blockDim.x + threadIdx.x;
  long long stride = (long long)gridDim.x * blockDim.x;
  // zero output
  for (long long i = gid; i < out_size; i += stride) dout[i] = 0.f;
  // zero h + c (contiguous region)
  unsigned* hz = (unsigned*)(ws + OFF_H);
  long long hcw = (long long)(SZ_H + SZ_C) / 4;
  for (long long i = gid; i < hcw; i += stride) hz[i] = 0u;
  // zero barrier counters + generation
  unsigned* bz = (unsigned*)(ws + OFF_BAR);
  for (long long i = gid; i < BAR_WORDS; i += stride) bz[i] = 0u;
  // bias sum
  float* bias = (float*)(ws + OFF_BIAS);
  for (long long i = gid; i < 4 * 2048; i += stride) bias[i] = bih[i] + bhh[i];
  // layer0 concat weights: [n][k<256]=W_ih0, [k in 256..768)=W_hh[0]
  unsigned short* w0 = (unsigned short*)(ws + OFF_W0);
  for (long long i = gid; i < 2048ll * 768; i += stride) {
    int n = (int)(i / 768), k = (int)(i % 768);
    float v = (k < 256) ? wih0[n * 256 + k] : whh[(long long)n * 512 + (k - 256)];
    w0[i] = f2bf(v);
  }
  // layers 1..3 concat: [k<512]=W_ih_rest[l-1], [k>=512]=W_hh[l]
  unsigned short* wr = (unsigned short*)(ws + OFF_W1);
  for (long long i = gid; i < 3ll * 2048 * 1024; i += stride) {
    int l0 = (int)(i >> 21);                 // 0..2 (layer-1)
    int rem = (int)(i & ((1 << 21) - 1));
    int n = rem >> 10, k = rem & 1023;
    float v = (k < 512) ? wihr[((long long)l0 * 2048 + n) * 512 + k]
                        : whh[((long long)(l0 + 1) * 2048 + n) * 512 + (k - 512)];
    wr[i] = f2bf(v);
  }
  // x -> bf16
  unsigned short* xb = (unsigned short*)(ws + OFF_XBF);
  for (long long i = gid; i < (long long)NB * SB * DB; i += stride) xb[i] = f2bf(x[i]);
}

// ---------------- kernel 2: segmentation + sort (1 block) ----------------
__global__ void k_seg(const void* __restrict__ maskp, char* __restrict__ ws,
                      float* __restrict__ dout, int Sp) {
  __shared__ unsigned bits[NB][64];
  __shared__ int hist[2050];
  __shared__ int sufx[2051];
  __shared__ int part[256];
  __shared__ unsigned metapk[NSEG_CAP];
  __shared__ int slotar[NSEG_CAP];
  __shared__ int rowcnt[NB];
  __shared__ int flagbits, nseg, maxlen;
  int tid = threadIdx.x;
  if (tid == 0) { flagbits = 0; nseg = 0; maxlen = 0; }
  for (int i = tid; i < 2050; i += 256) hist[i] = 0;
  __syncthreads();
  // ---- detect mask storage: u8 / i32 / f32 / 64-bit ----
  const unsigned* mw = (const unsigned*)maskp;
  int fb = 0;
  for (int i = tid; i < 8192; i += 256) {   // first 32768 bytes (always safe)
    unsigned w = mw[i];
    if (w == 0x3F800000u) fb |= 2;          // f32 1.0
    if (w == 0x3FF00000u) fb |= 4;          // f64 1.0 hi word
    if (w & 0xFFFFFF00u) fb |= 1;           // byte-packed evidence
    if ((i & 1) && w) fb |= 8;              // odd 32-bit word nonzero
  }
  if (fb) atomicOr(&flagbits, fb);
  __syncthreads();
  int f = flagbits;
  int kind = (f & 4) ? 3 : (f & 2) ? 2 : (f & 1) ? 0 : (f & 8) ? 1 : 3; // 3: 64-bit
  // ---- pack separator bits ----
  for (int w = tid; w < NB * 64; w += 256) {
    int row = w >> 6, j = w & 63;
    unsigned b = 0;
    int t0 = j * 32;
    for (int z = 0; z < 32; ++z) {
      long long idx = (long long)row * SB + t0 + z;
      bool sep;
      if (kind == 0)      sep = ((const unsigned char*)maskp)[idx] != 0;
      else if (kind == 1) sep = ((const int*)maskp)[idx] != 0;
      else if (kind == 2) sep = ((const float*)maskp)[idx] != 0.f;
      else                sep = ((const unsigned long long*)maskp)[idx] != 0ull;
      b |= (sep ? 1u : 0u) << z;
    }
    bits[row][j] = b;
  }
  __syncthreads();
  // ---- per-row segment extraction ----
  if (tid < NB) {
    int row = tid, i = 0, cnt = 0;
    for (int w = 0; w < 64; ++w) {
      unsigned b = bits[row][w];
      while (b) {
        int z = __ffs(b) - 1; b &= b - 1;
        int t = w * 32 + z;
        if (i != t) {
          int len = t - i;
          int idx = atomicAdd(&nseg, 1);
          if (idx < NSEG_CAP) { metapk[idx] = ((unsigned)row << 23) | ((unsigned)i << 12) | (unsigned)len; slotar[idx] = cnt; }
          atomicAdd(&hist[len], 1); atomicMax(&maxlen, len);
          cnt++;
        }
        i = t + 1;
      }
    }
    if (i != SB) {
      int len = SB - i;
      int idx = atomicAdd(&nseg, 1);
      if (idx < NSEG_CAP) { metapk[idx] = ((unsigned)row << 23) | ((unsigned)i << 12) | (unsigned)len; slotar[idx] = cnt; }
      atomicAdd(&hist[len], 1); atomicMax(&maxlen, len);
      cnt++;
    }
    rowcnt[row] = cnt;
  }
  __syncthreads();
  // ---- suffix sums: sufx[k] = #segs with len >= k ----
  {
    int lo = tid * 9, hi = lo + 9; if (hi > 2050) hi = 2050;
    int s = 0;
    for (int k = lo; k < hi; ++k) s += hist[k];
    part[tid] = s;
  }
  __syncthreads();
  {
    int tail = 0;
    for (int t2 = tid + 1; t2 < 256; ++t2) tail += part[t2];
    int lo = tid * 9, hi = lo + 9; if (hi > 2050) hi = 2050;
    int run = tail;
    for (int k = hi - 1; k >= lo; --k) { run += hist[k]; sufx[k] = run; }
  }
  __syncthreads();
  // active[r] = #segs with len > r
  int* act = (int*)(ws + OFF_ACT);
  for (int r = tid; r < 2048; r += 256) act[r] = sufx[r + 1];
  for (int i = tid; i < 2050; i += 256) hist[i] = 0;   // reuse as scatter counters
  __syncthreads();
  int NSEG = nseg < NSEG_CAP ? nseg : NSEG_CAP;
  int* srow = (int*)(ws + OFF_SROW);
  int* sstart = (int*)(ws + OFF_SSTART);
  int* slen = (int*)(ws + OFF_SLEN);
  int* sslot = (int*)(ws + OFF_SSLOT);
  for (int i = tid; i < NSEG; i += 256) {
    unsigned m = metapk[i];
    int len = m & 0xFFF, st = (m >> 12) & 0x7FF, row = (int)(m >> 23);
    int pos = sufx[len + 1] + atomicAdd(&hist[len], 1);  // sort by len desc
    srow[pos] = row; sstart[pos] = st; slen[pos] = len; sslot[pos] = slotar[i];
  }
  int* meta = (int*)(ws + OFF_META);
  if (tid == 0) { meta[0] = NSEG; meta[1] = maxlen; }
  __syncthreads();
  // out_mask: 1.0 where padding (~valid), else 0.0
  float* omask = dout + (long long)NB * Sp * EB;
  for (int i = tid; i < NB * Sp; i += 256) {
    int row = i / Sp, slot = i % Sp;
    omask[i] = (slot < rowcnt[row]) ? 0.f : 1.f;
  }
}

// ---------------- kernel 3: persistent diagonal-pipelined scan ----------------
__global__ void __launch_bounds__(256, 1)
k_main(char* __restrict__ ws, float* __restrict__ dout, int Sp) {
  __shared__ int act_s[2048];
  __shared__ int meta_s[2];
  int tid = threadIdx.x;
  {
    int* act = (int*)(ws + OFF_ACT);
    for (int i = tid; i < 2048; i += 256) act_s[i] = act[i];
    if (tid < 2) meta_s[tid] = ((int*)(ws + OFF_META))[tid];
  }
  __syncthreads();
  const int maxlen = meta_s[1];
  const int smax = maxlen + LB - 1;
  unsigned* cnt = (unsigned*)(ws + OFF_BAR);
  unsigned* gen = cnt + 2560;
  const int wave = tid >> 6, lane = tid & 63, l15 = lane & 15, lq = lane >> 4;
  const int* srow = (const int*)(ws + OFF_SROW);
  const int* sstart = (const int*)(ws + OFF_SSTART);
  const int* slen = (const int*)(ws + OFF_SLEN);
  const int* sslot = (const int*)(ws + OFF_SSLOT);
  const float* bias = (const float*)(ws + OFF_BIAS);
  const char* wsb = ws;

  for (int s = 0; s < smax; ++s) {
    int Ml[4], uoff[5]; uoff[0] = 0;
    for (int l = 0; l < 4; ++l) {
      int r = s - l;
      int M = (r >= 0 && r < maxlen) ? act_s[r] : 0;
      Ml[l] = M;
      uoff[l + 1] = uoff[l] + (((M + 63) >> 6) << 2);
    }
    int total = uoff[4];
    int P = (int)gridDim.x < total ? (int)gridDim.x : total;
    bool participant = (int)blockIdx.x < P;
    if (participant) {
      for (int u = blockIdx.x; u < total; u += P) {
        int l = (u >= uoff[2]) ? ((u >= uoff[3]) ? 3 : 2) : ((u >= uoff[1]) ? 1 : 0);
        int v = u - uoff[l];
        int ech = v & 3, mch = v >> 2;
        int r = s - l;
        int segbase = mch << 6;
        int Mv = Ml[l] - segbase; if (Mv > 64) Mv = 64;
        const int K = (l == 0) ? 768 : 1024;
        const int kb1 = (l == 0) ? 256 : 512;
        unsigned wl = (unsigned)((l == 0) ? OFF_W0 : (l == 1) ? OFF_W1 : (l == 2) ? OFF_W2 : OFF_W3);
        // per-lane A row base byte-offsets (lo = input side, hi = recurrent side)
        unsigned aoff_lo[4], aoff_hi[4];
        #pragma unroll
        for (int mf = 0; mf < 4; ++mf) {
          int m = (mf << 4) + l15;
          int sg = segbase + ((m < Mv) ? m : 0);
          unsigned lo;
          if (l == 0) {
            int rw = srow[sg], st = sstart[sg];
            lo = (unsigned)OFF_XBF + (((unsigned)(rw * SB + st + r)) * DB + 8u * lq) * 2u;
          } else {
            lo = (unsigned)OFF_H + ((((unsigned)((l - 1) * 2 + (r & 1)) * NSEG_CAP) + sg) * EB + 8u * lq) * 2u;
          }
          aoff_lo[mf] = lo;
          aoff_hi[mf] = (unsigned)OFF_H + ((((unsigned)(l * 2 + ((r - 1) & 1)) * NSEG_CAP) + sg) * EB + 8u * lq) * 2u;
        }
        const int e_lane0 = (ech << 7) + (wave << 5);
        unsigned boff[4][2];
        #pragma unroll
        for (int g = 0; g < 4; ++g)
          #pragma unroll
          for (int nf = 0; nf < 2; ++nf) {
            int n = g * 512 + e_lane0 + (nf << 4) + l15;
            boff[g][nf] = wl + ((unsigned)(n * K) + 8u * lq) * 2u;
          }
        f32x4 acc[4][4][2];
        #pragma unroll
        for (int mf = 0; mf < 4; ++mf)
          #pragma unroll
          for (int g = 0; g < 4; ++g)
            #pragma unroll
            for (int nf = 0; nf < 2; ++nf)
              acc[mf][g][nf] = (f32x4){0.f, 0.f, 0.f, 0.f};
        const int nk = K >> 5;
        #pragma unroll 2
        for (int kk = 0; kk < nk; ++kk) {
          int k0 = kk << 5;
          bool lo = (k0 < kb1);
          bf16x8 a[4], b[4][2];
          #pragma unroll
          for (int mf = 0; mf < 4; ++mf) {
            unsigned off = lo ? (aoff_lo[mf] + (unsigned)k0 * 2u)
                              : (aoff_hi[mf] + (unsigned)(k0 - kb1) * 2u);
            a[mf] = *(const bf16x8*)(wsb + off);
          }
          #pragma unroll
          for (int g = 0; g < 4; ++g)
            #pragma unroll
            for (int nf = 0; nf < 2; ++nf)
              b[g][nf] = *(const bf16x8*)(wsb + boff[g][nf] + (unsigned)k0 * 2u);
          #pragma unroll
          for (int mf = 0; mf < 4; ++mf)
            #pragma unroll
            for (int g = 0; g < 4; ++g)
              #pragma unroll
              for (int nf = 0; nf < 2; ++nf)
                acc[mf][g][nf] = __builtin_amdgcn_mfma_f32_16x16x32_bf16(
                    a[mf], b[g][nf], acc[mf][g][nf], 0, 0, 0);
        }
        // ---- epilogue: bias + activations + c/h update + output scatter ----
        float bs[4][2];
        #pragma unroll
        for (int g = 0; g < 4; ++g)
          #pragma unroll
          for (int nf = 0; nf < 2; ++nf)
            bs[g][nf] = bias[l * 2048 + g * 512 + e_lane0 + (nf << 4) + l15];
        #pragma unroll
        for (int mf = 0; mf < 4; ++mf)
          #pragma unroll
          for (int nf = 0; nf < 2; ++nf) {
            int e = e_lane0 + (nf << 4) + l15;
            #pragma unroll
            for (int reg = 0; reg < 4; ++reg) {
              int m = (mf << 4) + (lq << 2) + reg;
              if (m < Mv) {
                int sg = segbase + m;
                float gi = acc[mf][0][nf][reg] + bs[0][nf];
                float gf = acc[mf][1][nf][reg] + bs[1][nf];
                float gg = acc[mf][2][nf][reg] + bs[2][nf];
                float go = acc[mf][3][nf][reg] + bs[3][nf];
                float* cptr = (float*)(ws + OFF_C + (((unsigned)(l * NSEG_CAP + sg) * EB + e) * 4u));
                float cold = *cptr;
                float cnew = sigf(gf) * cold + sigf(gi) * tanhx(gg);
                float hnew = sigf(go) * tanhx(cnew);
                *cptr = cnew;
                *(unsigned short*)(ws + OFF_H + (((unsigned)(l * 2 + (r & 1)) * NSEG_CAP + sg) * EB + e) * 2u) = f2bf(hnew);
                if (l == 3) {
                  if (r == slen[sg] - 1) {
                    int rw = srow[sg], sl = sslot[sg];
                    if (sl < Sp) dout[(((long long)rw * Sp + sl) << 9) + e] = hnew;
                  }
                }
              }
            }
          }
      }
    }
    // ---- stage barrier (arrive if participant; everyone waits) ----
    __syncthreads();
    if (tid == 0) {
      if (participant) {
        __threadfence();
        unsigned old = __hip_atomic_fetch_add(&cnt[s], 1u, __ATOMIC_RELAXED, __HIP_MEMORY_SCOPE_AGENT);
        if (old == (unsigned)(P - 1))
          __hip_atomic_store(gen, (unsigned)(s + 1), __ATOMIC_RELEASE, __HIP_MEMORY_SCOPE_AGENT);
      }
      while (__hip_atomic_load(gen, __ATOMIC_RELAXED, __HIP_MEMORY_SCOPE_AGENT) < (unsigned)(s + 1))
        __builtin_amdgcn_s_sleep(2);
      __threadfence();
    }
    __syncthreads();
  }
}

extern "C" void kernel_launch(void* const* d_in, const int* in_sizes, int n_in,
                              void* d_out, int out_size, void* d_ws, size_t ws_size,
                              hipStream_t stream) {
  const float* x    = (const float*)d_in[0];
  const void*  mask = d_in[1];
  const float* wih0 = (const float*)d_in[2];
  const float* wihr = (const float*)d_in[3];
  const float* whh  = (const float*)d_in[4];
  const float* bih  = (const float*)d_in[5];
  const float* bhh  = (const float*)d_in[6];
  float* out = (float*)d_out;
  char* ws = (char*)d_ws;
  int Sp = out_size / (NB * (EB + 1));   // out = N*Sp*E  +  N*Sp mask

  k_conv<<<dim3(1024), dim3(256), 0, stream>>>(x, wih0, wihr, whh, bih, bhh, out, out_size, ws);
  k_seg<<<dim3(1), dim3(256), 0, stream>>>(mask, ws, out, Sp);
  k_main<<<dim3(GRID_MAIN), dim3(256), 0, stream>>>(ws, out, Sp);
}